// Round 11
// baseline (225.869 us; speedup 1.0000x reference)
//
#include <hip/hip_runtime.h>
#include <math.h>

#define BNUM 16
#define HNUM 512
#define WNUM 512
#define HW (HNUM*WNUM)            // 262144
#define NPLANE (BNUM*HW)          // 4194304
#define RR 8
#define KWIN 17
#define EPSF 1e-5f
#define THRESHF 0.8f
#define INV_KK (1.0f/289.0f)
#define INV_NUMEL (1.0f/12582912.0f)
#define YSEG 32
#define LROW 544                   // 528 + swizzle padding

__device__ __forceinline__ int swz(int i) { return i + (i >> 5); }

// ================= PRIMARY PATH: separable 2-pass, barrier-free vertical =================

// ---- K1: prep + horizontal 17-sums of I, p, I*p, I*I (one block per row, ONE barrier) ----
__global__ __launch_bounds__(128) void prep_h(
        const float* __restrict__ outp, const float* __restrict__ inp,
        float* __restrict__ PI, float* __restrict__ PS,
        float* __restrict__ HI, float* __restrict__ HP,
        float* __restrict__ HIp, float* __restrict__ HII) {
    __shared__ float LI[LROW], LP[LROW], LIp[LROW], LII[LROW];
    int t = threadIdx.x;
    int y = blockIdx.x & (HNUM - 1);
    int b = blockIdx.x >> 9;
    int x4 = t << 2;

    size_t rbase = (size_t)b * 3 * HW + (size_t)y * WNUM + x4;
    float4 a0 = *(const float4*)(inp + rbase);
    float4 a1 = *(const float4*)(inp + rbase + HW);
    float4 a2 = *(const float4*)(inp + rbase + 2 * HW);
    float4 c0 = *(const float4*)(outp + rbase);
    float4 c1 = *(const float4*)(outp + rbase + HW);
    float4 c2 = *(const float4*)(outp + rbase + 2 * HW);

    // zero pads: left px -8..-1, right px 512..519
    if (t < 8)   { int i = swz(t);        LI[i]=0.f; LP[i]=0.f; LIp[i]=0.f; LII[i]=0.f; }
    if (t >= 120){ int i = swz(t + 400);  LI[i]=0.f; LP[i]=0.f; LIp[i]=0.f; LII[i]=0.f; }

    float4 I4, S4;
#pragma unroll
    for (int j = 0; j < 4; ++j) {
        float ia = (&a0.x)[j], ib = (&a1.x)[j], ic = (&a2.x)[j];
        float i0 = (ia + 1.f) * 0.5f;
        float i1 = (ib + 1.f) * 0.5f;
        float i2 = (ic + 1.f) * 0.5f;
        float Iv = (i0 + i1 + i2) * (1.f / 3.f);
        float pv = (fmaxf(i0, fmaxf(i1, i2)) > THRESHF) ? 1.f : 0.f;
        (&I4.x)[j] = Iv;
        (&S4.x)[j] = 0.5f * (fabsf((&c0.x)[j] - ia) + fabsf((&c1.x)[j] - ib) + fabsf((&c2.x)[j] - ic));
        int ii = swz(x4 + j + 8);
        LI[ii] = Iv; LP[ii] = pv; LIp[ii] = Iv * pv; LII[ii] = Iv * Iv;
    }

    size_t po = (size_t)b * HW + (size_t)y * WNUM + x4;
    *(float4*)(PI + po) = I4;
    *(float4*)(PS + po) = S4;
    __syncthreads();

    float sI = 0.f, sP = 0.f, sIp = 0.f, sII = 0.f;
#pragma unroll
    for (int d = 0; d < KWIN; ++d) {
        int ii = swz(x4 + d);
        sI += LI[ii]; sP += LP[ii]; sIp += LIp[ii]; sII += LII[ii];
    }
    float4 oI, oP, oIp, oII;
    (&oI.x)[0]=sI; (&oP.x)[0]=sP; (&oIp.x)[0]=sIp; (&oII.x)[0]=sII;
#pragma unroll
    for (int j = 1; j < 4; ++j) {
        int im = swz(x4 + j - 1), ip = swz(x4 + j + 16);
        sI  += LI[ip]  - LI[im];
        sP  += LP[ip]  - LP[im];
        sIp += LIp[ip] - LIp[im];
        sII += LII[ip] - LII[im];
        (&oI.x)[j]=sI; (&oP.x)[j]=sP; (&oIp.x)[j]=sIp; (&oII.x)[j]=sII;
    }
    *(float4*)(HI  + po) = oI;
    *(float4*)(HP  + po) = oP;
    *(float4*)(HIp + po) = oIp;
    *(float4*)(HII + po) = oII;
}

// ---- K2: vertical 17-sums of H-planes -> a, b (barrier-free streaming scan) ----
__global__ __launch_bounds__(128) void v_ab(
        const float* __restrict__ HI, const float* __restrict__ HP,
        const float* __restrict__ HIp, const float* __restrict__ HII,
        float* __restrict__ Pa, float* __restrict__ Pb) {
    int t  = threadIdx.x;
    int x  = blockIdx.x * 128 + t;
    int y0 = blockIdx.y * YSEG;
    int b  = blockIdx.z;
    size_t base = (size_t)b * HW + x;
    const float* hi  = HI  + base;
    const float* hp  = HP  + base;
    const float* hip = HIp + base;
    const float* hii = HII + base;
    float* pa = Pa + base;
    float* pb = Pb + base;

    float vI = 0.f, vP = 0.f, vIp = 0.f, vII = 0.f;
#pragma unroll
    for (int d = -RR; d <= RR; ++d) {
        int y = y0 + d;
        if (y >= 0 && y < HNUM) {
            size_t o = (size_t)y * WNUM;
            vI += hi[o]; vP += hp[o]; vIp += hip[o]; vII += hii[o];
        }
    }
#pragma unroll 8
    for (int k = 0; k < YSEG; ++k) {
        int y = y0 + k;
        float mI  = vI  * INV_KK;
        float mP  = vP  * INV_KK;
        float mIp = vIp * INV_KK;
        float mII = vII * INV_KK;
        float cov = mIp - mI * mP;
        float var = mII - mI * mI;
        float a   = cov / (var + EPSF);
        float bb  = mP - a * mI;
        size_t o = (size_t)y * WNUM;
        pa[o] = a;
        pb[o] = bb;
        int yp = y + RR + 1, ym = y - RR;
        if (yp < HNUM) { size_t op = (size_t)yp * WNUM; vI += hi[op]; vP += hp[op]; vIp += hip[op]; vII += hii[op]; }
        if (ym >= 0)   { size_t om = (size_t)ym * WNUM; vI -= hi[om]; vP -= hp[om]; vIp -= hip[om]; vII -= hii[om]; }
    }
}

// ---- K3: horizontal 17-sums of a, b (one block per row, ONE barrier) ----
__global__ __launch_bounds__(128) void h_mask(
        const float* __restrict__ Pa, const float* __restrict__ Pb,
        float* __restrict__ Ha, float* __restrict__ Hb) {
    __shared__ float LA[LROW], LB[LROW];
    int t = threadIdx.x;
    int y = blockIdx.x & (HNUM - 1);
    int b = blockIdx.x >> 9;
    int x4 = t << 2;
    size_t po = (size_t)b * HW + (size_t)y * WNUM + x4;

    float4 va = *(const float4*)(Pa + po);
    float4 vb = *(const float4*)(Pb + po);

    if (t < 8)   { int i = swz(t);       LA[i]=0.f; LB[i]=0.f; }
    if (t >= 120){ int i = swz(t + 400); LA[i]=0.f; LB[i]=0.f; }
#pragma unroll
    for (int j = 0; j < 4; ++j) {
        int ii = swz(x4 + j + 8);
        LA[ii] = (&va.x)[j];
        LB[ii] = (&vb.x)[j];
    }
    __syncthreads();

    float sA = 0.f, sB = 0.f;
#pragma unroll
    for (int d = 0; d < KWIN; ++d) {
        int ii = swz(x4 + d);
        sA += LA[ii]; sB += LB[ii];
    }
    float4 oA, oB;
    (&oA.x)[0]=sA; (&oB.x)[0]=sB;
#pragma unroll
    for (int j = 1; j < 4; ++j) {
        int im = swz(x4 + j - 1), ip = swz(x4 + j + 16);
        sA += LA[ip] - LA[im];
        sB += LB[ip] - LB[im];
        (&oA.x)[j]=sA; (&oB.x)[j]=sB;
    }
    *(float4*)(Ha + po) = oA;
    *(float4*)(Hb + po) = oB;
}

// ---- K4: vertical 17-sums of Ha,Hb -> mask -> loss (barrier-free scan + reduce) ----
__global__ __launch_bounds__(128) void v_mask_loss(
        const float* __restrict__ Ha, const float* __restrict__ Hb,
        const float* __restrict__ PI, const float* __restrict__ PS,
        float* __restrict__ loss_out) {
    __shared__ float red[2];
    int t  = threadIdx.x;
    int x  = blockIdx.x * 128 + t;
    int y0 = blockIdx.y * YSEG;
    int b  = blockIdx.z;
    size_t base = (size_t)b * HW + x;
    const float* ha = Ha + base;
    const float* hb = Hb + base;
    const float* pi = PI + base;
    const float* ps = PS + base;

    float vA = 0.f, vB = 0.f;
#pragma unroll
    for (int d = -RR; d <= RR; ++d) {
        int y = y0 + d;
        if (y >= 0 && y < HNUM) {
            size_t o = (size_t)y * WNUM;
            vA += ha[o]; vB += hb[o];
        }
    }
    float partial = 0.f;
#pragma unroll 8
    for (int k = 0; k < YSEG; ++k) {
        int y = y0 + k;
        size_t o = (size_t)y * WNUM;
        float mA = vA * INV_KK;
        float mB = vB * INV_KK;
        float refined = mA * pi[o] + mB;
        float mask = fminf(fmaxf(refined, 0.f), 1.f);
        partial += mask * ps[o];
        int yp = y + RR + 1, ym = y - RR;
        if (yp < HNUM) { size_t op = (size_t)yp * WNUM; vA += ha[op]; vB += hb[op]; }
        if (ym >= 0)   { size_t om = (size_t)ym * WNUM; vA -= ha[om]; vB -= hb[om]; }
    }
#pragma unroll
    for (int off = 32; off > 0; off >>= 1)
        partial += __shfl_down(partial, off);
    if ((t & 63) == 0) red[t >> 6] = partial;
    __syncthreads();
    if (t == 0) atomicAdd(loss_out, (red[0] + red[1]) * INV_NUMEL);
}

// ================= FALLBACK PATH (R10, proven, 5 planes) =================
#define STRIP 128
#define SEG_AB 32
#define SEG_ML 16
#define RPG 2
#define RAMPG ((2*RR)/RPG)

__global__ __launch_bounds__(256) void prep_kernel(
        const float* __restrict__ outp, const float* __restrict__ inp,
        float* __restrict__ PI, float* __restrict__ PP, float* __restrict__ PS) {
    int pix = (blockIdx.x * 256 + threadIdx.x) * 4;
    if (pix >= NPLANE) return;
    int b = pix >> 18;
    int r = pix & (HW - 1);
    size_t base = (size_t)b * 3 * HW + r;
    float4 a0 = *(const float4*)(inp + base);
    float4 a1 = *(const float4*)(inp + base + HW);
    float4 a2 = *(const float4*)(inp + base + 2 * HW);
    float4 b0 = *(const float4*)(outp + base);
    float4 b1 = *(const float4*)(outp + base + HW);
    float4 b2 = *(const float4*)(outp + base + 2 * HW);
    float4 I4, P4, S4;
#define DOCOMP(M) { \
    float i0 = (a0.M + 1.f) * 0.5f; \
    float i1 = (a1.M + 1.f) * 0.5f; \
    float i2 = (a2.M + 1.f) * 0.5f; \
    I4.M = (i0 + i1 + i2) * (1.f/3.f); \
    float mx = fmaxf(i0, fmaxf(i1, i2)); \
    P4.M = (mx > THRESHF) ? 1.f : 0.f; \
    S4.M = 0.5f * (fabsf(b0.M - a0.M) + fabsf(b1.M - a1.M) + fabsf(b2.M - a2.M)); \
}
    DOCOMP(x) DOCOMP(y) DOCOMP(z) DOCOMP(w)
#undef DOCOMP
    size_t po = (size_t)b * HW + r;
    *(float4*)(PI + po) = I4;
    *(float4*)(PP + po) = P4;
    *(float4*)(PS + po) = S4;
}

__global__ __launch_bounds__(STRIP) void boxc_ab(
        const float* __restrict__ PI, const float* __restrict__ PP,
        float* __restrict__ PA, float* __restrict__ PB) {
    __shared__ float rowI[RPG][STRIP + 2 * RR];
    __shared__ float rowP[RPG][STRIP + 2 * RR];
    __shared__ float ring[4][KWIN][STRIP];
    int t  = threadIdx.x;
    int x0 = blockIdx.x * STRIP;
    int ys = blockIdx.y * SEG_AB;
    int b  = blockIdx.z;
    const float* Ib = PI + (size_t)b * HW;
    const float* Pb = PP + (size_t)b * HW;
    float* Ab = PA + (size_t)b * HW;
    float* Bb = PB + (size_t)b * HW;
    for (int i = t; i < 4 * KWIN * STRIP; i += STRIP) (&ring[0][0][0])[i] = 0.f;
    int xg  = x0 - RR + t;
    bool xok  = (xg >= 0) && (xg < WNUM);
    int xg2 = x0 - RR + STRIP + t;
    bool x2ok = (t < 2 * RR) && (xg2 < WNUM);
    float vI = 0.f, vP = 0.f, vIp = 0.f, vII = 0.f;
    int slot = 0;
    const int NG = (SEG_AB + 2 * RR) / RPG;
    float pi0[RPG], pp0[RPG], pi1[RPG], pp1[RPG];
#pragma unroll
    for (int r = 0; r < RPG; ++r) {
        pi0[r]=0.f; pp0[r]=0.f; pi1[r]=0.f; pp1[r]=0.f;
        int y = ys - RR + r;
        if (y >= 0 && y < HNUM) {
            size_t ro = (size_t)y * WNUM;
            if (xok)  { pi0[r] = Ib[ro + xg];  pp0[r] = Pb[ro + xg]; }
            if (x2ok) { pi1[r] = Ib[ro + xg2]; pp1[r] = Pb[ro + xg2]; }
        }
    }
    for (int g = 0; g < NG; ++g) {
#pragma unroll
        for (int r = 0; r < RPG; ++r) { rowI[r][t] = pi0[r]; rowP[r][t] = pp0[r]; }
        if (t < 2 * RR) {
#pragma unroll
            for (int r = 0; r < RPG; ++r) { rowI[r][STRIP+t] = pi1[r]; rowP[r][STRIP+t] = pp1[r]; }
        }
#pragma unroll
        for (int r = 0; r < RPG; ++r) { pi0[r]=0.f; pp0[r]=0.f; pi1[r]=0.f; pp1[r]=0.f; }
        if (g + 1 < NG) {
#pragma unroll
            for (int r = 0; r < RPG; ++r) {
                int y = ys - RR + (g + 1) * RPG + r;
                if (y >= 0 && y < HNUM) {
                    size_t ro = (size_t)y * WNUM;
                    if (xok)  { pi0[r] = Ib[ro + xg];  pp0[r] = Pb[ro + xg]; }
                    if (x2ok) { pi1[r] = Ib[ro + xg2]; pp1[r] = Pb[ro + xg2]; }
                }
            }
        }
        __syncthreads();
        bool emit = (g >= RAMPG);
#pragma unroll
        for (int r = 0; r < RPG; ++r) {
            float sI=0.f, sP=0.f, sIp=0.f, sII=0.f;
#pragma unroll
            for (int d = 0; d < KWIN; ++d) {
                float iv = rowI[r][t + d];
                float pv = rowP[r][t + d];
                sI += iv; sP += pv; sIp += iv * pv; sII += iv * iv;
            }
            vI  += sI  - ring[0][slot][t]; ring[0][slot][t] = sI;
            vP  += sP  - ring[1][slot][t]; ring[1][slot][t] = sP;
            vIp += sIp - ring[2][slot][t]; ring[2][slot][t] = sIp;
            vII += sII - ring[3][slot][t]; ring[3][slot][t] = sII;
            slot = (slot + 1 == KWIN) ? 0 : slot + 1;
            if (emit) {
                int k = g * RPG + r;
                int yout = ys + k - 2 * RR;
                float mI  = vI  * INV_KK;
                float mP  = vP  * INV_KK;
                float mIp = vIp * INV_KK;
                float mII = vII * INV_KK;
                float cov = mIp - mI * mP;
                float var = mII - mI * mI;
                float a   = cov / (var + EPSF);
                float bb  = mP - a * mI;
                size_t off = (size_t)yout * WNUM + x0 + t;
                Ab[off] = a;
                Bb[off] = bb;
            }
        }
        __syncthreads();
    }
}

__global__ __launch_bounds__(STRIP) void boxc_mask_loss(
        const float* __restrict__ PA, const float* __restrict__ PB,
        const float* __restrict__ PI, const float* __restrict__ PS,
        float* __restrict__ loss_out) {
    __shared__ float rowA[RPG][STRIP + 2 * RR];
    __shared__ float rowB[RPG][STRIP + 2 * RR];
    __shared__ float ring[2][KWIN][STRIP];
    __shared__ float red[2];
    int t  = threadIdx.x;
    int x0 = blockIdx.x * STRIP;
    int ys = blockIdx.y * SEG_ML;
    int b  = blockIdx.z;
    const float* Ab = PA + (size_t)b * HW;
    const float* Bb = PB + (size_t)b * HW;
    const float* Ib = PI + (size_t)b * HW;
    const float* Sb = PS + (size_t)b * HW;
    for (int i = t; i < 2 * KWIN * STRIP; i += STRIP) (&ring[0][0][0])[i] = 0.f;
    int xg  = x0 - RR + t;
    bool xok  = (xg >= 0) && (xg < WNUM);
    int xg2 = x0 - RR + STRIP + t;
    bool x2ok = (t < 2 * RR) && (xg2 < WNUM);
    float vA = 0.f, vB = 0.f;
    int slot = 0;
    float partial = 0.f;
    const int NG = (SEG_ML + 2 * RR) / RPG;
    float pa0[RPG], pb0[RPG], pa1[RPG], pb1[RPG];
#pragma unroll
    for (int r = 0; r < RPG; ++r) {
        pa0[r]=0.f; pb0[r]=0.f; pa1[r]=0.f; pb1[r]=0.f;
        int y = ys - RR + r;
        if (y >= 0 && y < HNUM) {
            size_t ro = (size_t)y * WNUM;
            if (xok)  { pa0[r] = Ab[ro + xg];  pb0[r] = Bb[ro + xg]; }
            if (x2ok) { pa1[r] = Ab[ro + xg2]; pb1[r] = Bb[ro + xg2]; }
        }
    }
    for (int g = 0; g < NG; ++g) {
#pragma unroll
        for (int r = 0; r < RPG; ++r) { rowA[r][t] = pa0[r]; rowB[r][t] = pb0[r]; }
        if (t < 2 * RR) {
#pragma unroll
            for (int r = 0; r < RPG; ++r) { rowA[r][STRIP+t] = pa1[r]; rowB[r][STRIP+t] = pb1[r]; }
        }
#pragma unroll
        for (int r = 0; r < RPG; ++r) { pa0[r]=0.f; pb0[r]=0.f; pa1[r]=0.f; pb1[r]=0.f; }
        if (g + 1 < NG) {
#pragma unroll
            for (int r = 0; r < RPG; ++r) {
                int y = ys - RR + (g + 1) * RPG + r;
                if (y >= 0 && y < HNUM) {
                    size_t ro = (size_t)y * WNUM;
                    if (xok)  { pa0[r] = Ab[ro + xg];  pb0[r] = Bb[ro + xg]; }
                    if (x2ok) { pa1[r] = Ab[ro + xg2]; pb1[r] = Bb[ro + xg2]; }
                }
            }
        }
        __syncthreads();
        bool emit = (g >= RAMPG);
#pragma unroll
        for (int r = 0; r < RPG; ++r) {
            float sA=0.f, sB=0.f;
#pragma unroll
            for (int d = 0; d < KWIN; ++d) {
                sA += rowA[r][t + d];
                sB += rowB[r][t + d];
            }
            vA += sA - ring[0][slot][t]; ring[0][slot][t] = sA;
            vB += sB - ring[1][slot][t]; ring[1][slot][t] = sB;
            slot = (slot + 1 == KWIN) ? 0 : slot + 1;
            if (emit) {
                int k = g * RPG + r;
                int yout = ys + k - 2 * RR;
                float mA = vA * INV_KK;
                float mB = vB * INV_KK;
                size_t off = (size_t)yout * WNUM + x0 + t;
                float refined = mA * Ib[off] + mB;
                float mask = fminf(fmaxf(refined, 0.f), 1.f);
                partial += mask * Sb[off];
            }
        }
        __syncthreads();
    }
#pragma unroll
    for (int off = 32; off > 0; off >>= 1)
        partial += __shfl_down(partial, off);
    if ((t & 63) == 0) red[t >> 6] = partial;
    __syncthreads();
    if (t == 0) atomicAdd(loss_out, (red[0] + red[1]) * INV_NUMEL);
}

extern "C" void kernel_launch(void* const* d_in, const int* in_sizes, int n_in,
                              void* d_out, int out_size, void* d_ws, size_t ws_size,
                              hipStream_t stream) {
    const float* outp = (const float*)d_in[0];
    const float* inp  = (const float*)d_in[1];
    float* ws = (float*)d_ws;

    hipMemsetAsync(d_out, 0, sizeof(float), stream);

    // ws_size is constant across calls -> deterministic branch, graph-capture safe.
    if (ws_size >= (size_t)8 * NPLANE * sizeof(float)) {
        float* PI  = ws;
        float* PS  = ws + (size_t)1 * NPLANE;
        float* HI  = ws + (size_t)2 * NPLANE;
        float* HP  = ws + (size_t)3 * NPLANE;
        float* HIp = ws + (size_t)4 * NPLANE;
        float* HII = ws + (size_t)5 * NPLANE;
        float* Pa  = ws + (size_t)6 * NPLANE;
        float* Pb  = ws + (size_t)7 * NPLANE;
        float* Ha  = HI;   // HI/HP dead after v_ab
        float* Hb  = HP;

        prep_h<<<BNUM * HNUM, 128, 0, stream>>>(outp, inp, PI, PS, HI, HP, HIp, HII);
        dim3 vg(WNUM / 128, HNUM / YSEG, BNUM);   // 4 x 16 x 16 = 1024
        v_ab<<<vg, 128, 0, stream>>>(HI, HP, HIp, HII, Pa, Pb);
        h_mask<<<BNUM * HNUM, 128, 0, stream>>>(Pa, Pb, Ha, Hb);
        v_mask_loss<<<vg, 128, 0, stream>>>(Ha, Hb, PI, PS, (float*)d_out);
    } else {
        float* PI = ws;
        float* PP = ws + (size_t)NPLANE;
        float* PS = ws + (size_t)2 * NPLANE;
        float* PA = ws + (size_t)3 * NPLANE;
        float* PB = ws + (size_t)4 * NPLANE;
        prep_kernel<<<NPLANE / (256 * 4), 256, 0, stream>>>(outp, inp, PI, PP, PS);
        dim3 grid_ab(WNUM / STRIP, HNUM / SEG_AB, BNUM);
        boxc_ab<<<grid_ab, STRIP, 0, stream>>>(PI, PP, PA, PB);
        dim3 grid_ml(WNUM / STRIP, HNUM / SEG_ML, BNUM);
        boxc_mask_loss<<<grid_ml, STRIP, 0, stream>>>(PA, PB, PI, PS, (float*)d_out);
    }
}

// Round 12
// 203.666 us; speedup vs baseline: 1.1090x; 1.1090x over previous
//
#include <hip/hip_runtime.h>
#include <math.h>

#define BNUM 16
#define HNUM 512
#define WNUM 512
#define HW (HNUM*WNUM)            // 262144
#define NPLANE (BNUM*HW)          // 4194304
#define RR 8
#define KWIN 17
#define EPSF 1e-5f
#define THRESHF 0.8f
#define INV_KK (1.0f/289.0f)
#define INV_NUMEL (1.0f/12582912.0f)
#define YSEG 32
#define GRP 8                      // rows per prefetch group in V-kernels
#define LROW 544                   // 528 + swizzle padding

__device__ __forceinline__ int swz(int i) { return i + (i >> 5); }

// ================= PRIMARY PATH: separable 2-pass, barrier-free vertical =================

// ---- K1: prep + horizontal 17-sums of I, p, I*p, I*I (one block per row, ONE barrier) ----
__global__ __launch_bounds__(128) void prep_h(
        const float* __restrict__ outp, const float* __restrict__ inp,
        float* __restrict__ PI, float* __restrict__ PS,
        float* __restrict__ HI, float* __restrict__ HP,
        float* __restrict__ HIp, float* __restrict__ HII) {
    __shared__ float LI[LROW], LP[LROW], LIp[LROW], LII[LROW];
    int t = threadIdx.x;
    int y = blockIdx.x & (HNUM - 1);
    int b = blockIdx.x >> 9;
    int x4 = t << 2;

    size_t rbase = (size_t)b * 3 * HW + (size_t)y * WNUM + x4;
    float4 a0 = *(const float4*)(inp + rbase);
    float4 a1 = *(const float4*)(inp + rbase + HW);
    float4 a2 = *(const float4*)(inp + rbase + 2 * HW);
    float4 c0 = *(const float4*)(outp + rbase);
    float4 c1 = *(const float4*)(outp + rbase + HW);
    float4 c2 = *(const float4*)(outp + rbase + 2 * HW);

    if (t < 8)   { int i = swz(t);        LI[i]=0.f; LP[i]=0.f; LIp[i]=0.f; LII[i]=0.f; }
    if (t >= 120){ int i = swz(t + 400);  LI[i]=0.f; LP[i]=0.f; LIp[i]=0.f; LII[i]=0.f; }

    float4 I4, S4;
#pragma unroll
    for (int j = 0; j < 4; ++j) {
        float ia = (&a0.x)[j], ib = (&a1.x)[j], ic = (&a2.x)[j];
        float i0 = (ia + 1.f) * 0.5f;
        float i1 = (ib + 1.f) * 0.5f;
        float i2 = (ic + 1.f) * 0.5f;
        float Iv = (i0 + i1 + i2) * (1.f / 3.f);
        float pv = (fmaxf(i0, fmaxf(i1, i2)) > THRESHF) ? 1.f : 0.f;
        (&I4.x)[j] = Iv;
        (&S4.x)[j] = 0.5f * (fabsf((&c0.x)[j] - ia) + fabsf((&c1.x)[j] - ib) + fabsf((&c2.x)[j] - ic));
        int ii = swz(x4 + j + 8);
        LI[ii] = Iv; LP[ii] = pv; LIp[ii] = Iv * pv; LII[ii] = Iv * Iv;
    }

    size_t po = (size_t)b * HW + (size_t)y * WNUM + x4;
    *(float4*)(PI + po) = I4;
    *(float4*)(PS + po) = S4;
    __syncthreads();

    float sI = 0.f, sP = 0.f, sIp = 0.f, sII = 0.f;
#pragma unroll
    for (int d = 0; d < KWIN; ++d) {
        int ii = swz(x4 + d);
        sI += LI[ii]; sP += LP[ii]; sIp += LIp[ii]; sII += LII[ii];
    }
    float4 oI, oP, oIp, oII;
    (&oI.x)[0]=sI; (&oP.x)[0]=sP; (&oIp.x)[0]=sIp; (&oII.x)[0]=sII;
#pragma unroll
    for (int j = 1; j < 4; ++j) {
        int im = swz(x4 + j - 1), ip = swz(x4 + j + 16);
        sI  += LI[ip]  - LI[im];
        sP  += LP[ip]  - LP[im];
        sIp += LIp[ip] - LIp[im];
        sII += LII[ip] - LII[im];
        (&oI.x)[j]=sI; (&oP.x)[j]=sP; (&oIp.x)[j]=sIp; (&oII.x)[j]=sII;
    }
    *(float4*)(HI  + po) = oI;
    *(float4*)(HP  + po) = oP;
    *(float4*)(HIp + po) = oIp;
    *(float4*)(HII + po) = oII;
}

// ---- K2: vertical 17-sums of H-planes -> a, b ----
// Barrier-free streaming scan; loads batched 8 rows deep (64 independent loads
// per group) so HBM latency is covered even at 2 waves/SIMD grid occupancy.
__global__ __launch_bounds__(128) void v_ab(
        const float* __restrict__ HI, const float* __restrict__ HP,
        const float* __restrict__ HIp, const float* __restrict__ HII,
        float* __restrict__ Pa, float* __restrict__ Pb) {
    int t  = threadIdx.x;
    int x  = blockIdx.x * 128 + t;
    int y0 = blockIdx.y * YSEG;
    int b  = blockIdx.z;
    size_t base = (size_t)b * HW + x;
    const float* hi  = HI  + base;
    const float* hp  = HP  + base;
    const float* hip = HIp + base;
    const float* hii = HII + base;
    float* pa = Pa + base;
    float* pb = Pb + base;

    float vI = 0.f, vP = 0.f, vIp = 0.f, vII = 0.f;
#pragma unroll
    for (int d = -RR; d <= RR; ++d) {
        int y = y0 + d;
        if (y >= 0 && y < HNUM) {
            size_t o = (size_t)y * WNUM;
            vI += hi[o]; vP += hp[o]; vIp += hip[o]; vII += hii[o];
        }
    }
    for (int k0 = 0; k0 < YSEG; k0 += GRP) {
        float aI[GRP], aP[GRP], aIp[GRP], aII[GRP];
        float sI[GRP], sP[GRP], sIp[GRP], sII[GRP];
#pragma unroll
        for (int r = 0; r < GRP; ++r) {
            int yp = y0 + k0 + r + RR + 1;
            int ym = y0 + k0 + r - RR;
            if (yp < HNUM) { size_t o = (size_t)yp * WNUM; aI[r]=hi[o]; aP[r]=hp[o]; aIp[r]=hip[o]; aII[r]=hii[o]; }
            else           { aI[r]=0.f; aP[r]=0.f; aIp[r]=0.f; aII[r]=0.f; }
            if (ym >= 0)   { size_t o = (size_t)ym * WNUM; sI[r]=hi[o]; sP[r]=hp[o]; sIp[r]=hip[o]; sII[r]=hii[o]; }
            else           { sI[r]=0.f; sP[r]=0.f; sIp[r]=0.f; sII[r]=0.f; }
        }
#pragma unroll
        for (int r = 0; r < GRP; ++r) {
            int y = y0 + k0 + r;
            float mI  = vI  * INV_KK;
            float mP  = vP  * INV_KK;
            float mIp = vIp * INV_KK;
            float mII = vII * INV_KK;
            float cov = mIp - mI * mP;
            float var = mII - mI * mI;
            float a   = cov / (var + EPSF);
            float bb  = mP - a * mI;
            size_t o = (size_t)y * WNUM;
            pa[o] = a;
            pb[o] = bb;
            vI += aI[r] - sI[r]; vP += aP[r] - sP[r]; vIp += aIp[r] - sIp[r]; vII += aII[r] - sII[r];
        }
    }
}

// ---- K3: horizontal 17-sums of a, b (one block per row, ONE barrier) ----
__global__ __launch_bounds__(128) void h_mask(
        const float* __restrict__ Pa, const float* __restrict__ Pb,
        float* __restrict__ Ha, float* __restrict__ Hb) {
    __shared__ float LA[LROW], LB[LROW];
    int t = threadIdx.x;
    int y = blockIdx.x & (HNUM - 1);
    int b = blockIdx.x >> 9;
    int x4 = t << 2;
    size_t po = (size_t)b * HW + (size_t)y * WNUM + x4;

    float4 va = *(const float4*)(Pa + po);
    float4 vb = *(const float4*)(Pb + po);

    if (t < 8)   { int i = swz(t);       LA[i]=0.f; LB[i]=0.f; }
    if (t >= 120){ int i = swz(t + 400); LA[i]=0.f; LB[i]=0.f; }
#pragma unroll
    for (int j = 0; j < 4; ++j) {
        int ii = swz(x4 + j + 8);
        LA[ii] = (&va.x)[j];
        LB[ii] = (&vb.x)[j];
    }
    __syncthreads();

    float sA = 0.f, sB = 0.f;
#pragma unroll
    for (int d = 0; d < KWIN; ++d) {
        int ii = swz(x4 + d);
        sA += LA[ii]; sB += LB[ii];
    }
    float4 oA, oB;
    (&oA.x)[0]=sA; (&oB.x)[0]=sB;
#pragma unroll
    for (int j = 1; j < 4; ++j) {
        int im = swz(x4 + j - 1), ip = swz(x4 + j + 16);
        sA += LA[ip] - LA[im];
        sB += LB[ip] - LB[im];
        (&oA.x)[j]=sA; (&oB.x)[j]=sB;
    }
    *(float4*)(Ha + po) = oA;
    *(float4*)(Hb + po) = oB;
}

// ---- K4: vertical 17-sums of Ha,Hb -> mask -> loss (batched loads, no barriers) ----
__global__ __launch_bounds__(128) void v_mask_loss(
        const float* __restrict__ Ha, const float* __restrict__ Hb,
        const float* __restrict__ PI, const float* __restrict__ PS,
        float* __restrict__ loss_out) {
    __shared__ float red[2];
    int t  = threadIdx.x;
    int x  = blockIdx.x * 128 + t;
    int y0 = blockIdx.y * YSEG;
    int b  = blockIdx.z;
    size_t base = (size_t)b * HW + x;
    const float* ha = Ha + base;
    const float* hb = Hb + base;
    const float* pi = PI + base;
    const float* ps = PS + base;

    float vA = 0.f, vB = 0.f;
#pragma unroll
    for (int d = -RR; d <= RR; ++d) {
        int y = y0 + d;
        if (y >= 0 && y < HNUM) {
            size_t o = (size_t)y * WNUM;
            vA += ha[o]; vB += hb[o];
        }
    }
    float partial = 0.f;
    for (int k0 = 0; k0 < YSEG; k0 += GRP) {
        float aA[GRP], aB[GRP], sA[GRP], sB[GRP], vi[GRP], vs[GRP];
#pragma unroll
        for (int r = 0; r < GRP; ++r) {
            int y  = y0 + k0 + r;
            int yp = y + RR + 1;
            int ym = y - RR;
            size_t o = (size_t)y * WNUM;
            vi[r] = pi[o];
            vs[r] = ps[o];
            if (yp < HNUM) { size_t op = (size_t)yp * WNUM; aA[r]=ha[op]; aB[r]=hb[op]; }
            else           { aA[r]=0.f; aB[r]=0.f; }
            if (ym >= 0)   { size_t om = (size_t)ym * WNUM; sA[r]=ha[om]; sB[r]=hb[om]; }
            else           { sA[r]=0.f; sB[r]=0.f; }
        }
#pragma unroll
        for (int r = 0; r < GRP; ++r) {
            float mA = vA * INV_KK;
            float mB = vB * INV_KK;
            float refined = mA * vi[r] + mB;
            float mask = fminf(fmaxf(refined, 0.f), 1.f);
            partial += mask * vs[r];
            vA += aA[r] - sA[r];
            vB += aB[r] - sB[r];
        }
    }
#pragma unroll
    for (int off = 32; off > 0; off >>= 1)
        partial += __shfl_down(partial, off);
    if ((t & 63) == 0) red[t >> 6] = partial;
    __syncthreads();
    if (t == 0) atomicAdd(loss_out, (red[0] + red[1]) * INV_NUMEL);
}

// ================= FALLBACK PATH (R10, proven, 5 planes) =================
#define STRIP 128
#define SEG_AB 32
#define SEG_ML 16
#define RPG 2
#define RAMPG ((2*RR)/RPG)

__global__ __launch_bounds__(256) void prep_kernel(
        const float* __restrict__ outp, const float* __restrict__ inp,
        float* __restrict__ PI, float* __restrict__ PP, float* __restrict__ PS) {
    int pix = (blockIdx.x * 256 + threadIdx.x) * 4;
    if (pix >= NPLANE) return;
    int b = pix >> 18;
    int r = pix & (HW - 1);
    size_t base = (size_t)b * 3 * HW + r;
    float4 a0 = *(const float4*)(inp + base);
    float4 a1 = *(const float4*)(inp + base + HW);
    float4 a2 = *(const float4*)(inp + base + 2 * HW);
    float4 b0 = *(const float4*)(outp + base);
    float4 b1 = *(const float4*)(outp + base + HW);
    float4 b2 = *(const float4*)(outp + base + 2 * HW);
    float4 I4, P4, S4;
#define DOCOMP(M) { \
    float i0 = (a0.M + 1.f) * 0.5f; \
    float i1 = (a1.M + 1.f) * 0.5f; \
    float i2 = (a2.M + 1.f) * 0.5f; \
    I4.M = (i0 + i1 + i2) * (1.f/3.f); \
    float mx = fmaxf(i0, fmaxf(i1, i2)); \
    P4.M = (mx > THRESHF) ? 1.f : 0.f; \
    S4.M = 0.5f * (fabsf(b0.M - a0.M) + fabsf(b1.M - a1.M) + fabsf(b2.M - a2.M)); \
}
    DOCOMP(x) DOCOMP(y) DOCOMP(z) DOCOMP(w)
#undef DOCOMP
    size_t po = (size_t)b * HW + r;
    *(float4*)(PI + po) = I4;
    *(float4*)(PP + po) = P4;
    *(float4*)(PS + po) = S4;
}

__global__ __launch_bounds__(STRIP) void boxc_ab(
        const float* __restrict__ PI, const float* __restrict__ PP,
        float* __restrict__ PA, float* __restrict__ PB) {
    __shared__ float rowI[RPG][STRIP + 2 * RR];
    __shared__ float rowP[RPG][STRIP + 2 * RR];
    __shared__ float ring[4][KWIN][STRIP];
    int t  = threadIdx.x;
    int x0 = blockIdx.x * STRIP;
    int ys = blockIdx.y * SEG_AB;
    int b  = blockIdx.z;
    const float* Ib = PI + (size_t)b * HW;
    const float* Pb = PP + (size_t)b * HW;
    float* Ab = PA + (size_t)b * HW;
    float* Bb = PB + (size_t)b * HW;
    for (int i = t; i < 4 * KWIN * STRIP; i += STRIP) (&ring[0][0][0])[i] = 0.f;
    int xg  = x0 - RR + t;
    bool xok  = (xg >= 0) && (xg < WNUM);
    int xg2 = x0 - RR + STRIP + t;
    bool x2ok = (t < 2 * RR) && (xg2 < WNUM);
    float vI = 0.f, vP = 0.f, vIp = 0.f, vII = 0.f;
    int slot = 0;
    const int NG = (SEG_AB + 2 * RR) / RPG;
    float pi0[RPG], pp0[RPG], pi1[RPG], pp1[RPG];
#pragma unroll
    for (int r = 0; r < RPG; ++r) {
        pi0[r]=0.f; pp0[r]=0.f; pi1[r]=0.f; pp1[r]=0.f;
        int y = ys - RR + r;
        if (y >= 0 && y < HNUM) {
            size_t ro = (size_t)y * WNUM;
            if (xok)  { pi0[r] = Ib[ro + xg];  pp0[r] = Pb[ro + xg]; }
            if (x2ok) { pi1[r] = Ib[ro + xg2]; pp1[r] = Pb[ro + xg2]; }
        }
    }
    for (int g = 0; g < NG; ++g) {
#pragma unroll
        for (int r = 0; r < RPG; ++r) { rowI[r][t] = pi0[r]; rowP[r][t] = pp0[r]; }
        if (t < 2 * RR) {
#pragma unroll
            for (int r = 0; r < RPG; ++r) { rowI[r][STRIP+t] = pi1[r]; rowP[r][STRIP+t] = pp1[r]; }
        }
#pragma unroll
        for (int r = 0; r < RPG; ++r) { pi0[r]=0.f; pp0[r]=0.f; pi1[r]=0.f; pp1[r]=0.f; }
        if (g + 1 < NG) {
#pragma unroll
            for (int r = 0; r < RPG; ++r) {
                int y = ys - RR + (g + 1) * RPG + r;
                if (y >= 0 && y < HNUM) {
                    size_t ro = (size_t)y * WNUM;
                    if (xok)  { pi0[r] = Ib[ro + xg];  pp0[r] = Pb[ro + xg]; }
                    if (x2ok) { pi1[r] = Ib[ro + xg2]; pp1[r] = Pb[ro + xg2]; }
                }
            }
        }
        __syncthreads();
        bool emit = (g >= RAMPG);
#pragma unroll
        for (int r = 0; r < RPG; ++r) {
            float sI=0.f, sP=0.f, sIp=0.f, sII=0.f;
#pragma unroll
            for (int d = 0; d < KWIN; ++d) {
                float iv = rowI[r][t + d];
                float pv = rowP[r][t + d];
                sI += iv; sP += pv; sIp += iv * pv; sII += iv * iv;
            }
            vI  += sI  - ring[0][slot][t]; ring[0][slot][t] = sI;
            vP  += sP  - ring[1][slot][t]; ring[1][slot][t] = sP;
            vIp += sIp - ring[2][slot][t]; ring[2][slot][t] = sIp;
            vII += sII - ring[3][slot][t]; ring[3][slot][t] = sII;
            slot = (slot + 1 == KWIN) ? 0 : slot + 1;
            if (emit) {
                int k = g * RPG + r;
                int yout = ys + k - 2 * RR;
                float mI  = vI  * INV_KK;
                float mP  = vP  * INV_KK;
                float mIp = vIp * INV_KK;
                float mII = vII * INV_KK;
                float cov = mIp - mI * mP;
                float var = mII - mI * mI;
                float a   = cov / (var + EPSF);
                float bb  = mP - a * mI;
                size_t off = (size_t)yout * WNUM + x0 + t;
                Ab[off] = a;
                Bb[off] = bb;
            }
        }
        __syncthreads();
    }
}

__global__ __launch_bounds__(STRIP) void boxc_mask_loss(
        const float* __restrict__ PA, const float* __restrict__ PB,
        const float* __restrict__ PI, const float* __restrict__ PS,
        float* __restrict__ loss_out) {
    __shared__ float rowA[RPG][STRIP + 2 * RR];
    __shared__ float rowB[RPG][STRIP + 2 * RR];
    __shared__ float ring[2][KWIN][STRIP];
    __shared__ float red[2];
    int t  = threadIdx.x;
    int x0 = blockIdx.x * STRIP;
    int ys = blockIdx.y * SEG_ML;
    int b  = blockIdx.z;
    const float* Ab = PA + (size_t)b * HW;
    const float* Bb = PB + (size_t)b * HW;
    const float* Ib = PI + (size_t)b * HW;
    const float* Sb = PS + (size_t)b * HW;
    for (int i = t; i < 2 * KWIN * STRIP; i += STRIP) (&ring[0][0][0])[i] = 0.f;
    int xg  = x0 - RR + t;
    bool xok  = (xg >= 0) && (xg < WNUM);
    int xg2 = x0 - RR + STRIP + t;
    bool x2ok = (t < 2 * RR) && (xg2 < WNUM);
    float vA = 0.f, vB = 0.f;
    int slot = 0;
    float partial = 0.f;
    const int NG = (SEG_ML + 2 * RR) / RPG;
    float pa0[RPG], pb0[RPG], pa1[RPG], pb1[RPG];
#pragma unroll
    for (int r = 0; r < RPG; ++r) {
        pa0[r]=0.f; pb0[r]=0.f; pa1[r]=0.f; pb1[r]=0.f;
        int y = ys - RR + r;
        if (y >= 0 && y < HNUM) {
            size_t ro = (size_t)y * WNUM;
            if (xok)  { pa0[r] = Ab[ro + xg];  pb0[r] = Bb[ro + xg]; }
            if (x2ok) { pa1[r] = Ab[ro + xg2]; pb1[r] = Bb[ro + xg2]; }
        }
    }
    for (int g = 0; g < NG; ++g) {
#pragma unroll
        for (int r = 0; r < RPG; ++r) { rowA[r][t] = pa0[r]; rowB[r][t] = pb0[r]; }
        if (t < 2 * RR) {
#pragma unroll
            for (int r = 0; r < RPG; ++r) { rowA[r][STRIP+t] = pa1[r]; rowB[r][STRIP+t] = pb1[r]; }
        }
#pragma unroll
        for (int r = 0; r < RPG; ++r) { pa0[r]=0.f; pb0[r]=0.f; pa1[r]=0.f; pb1[r]=0.f; }
        if (g + 1 < NG) {
#pragma unroll
            for (int r = 0; r < RPG; ++r) {
                int y = ys - RR + (g + 1) * RPG + r;
                if (y >= 0 && y < HNUM) {
                    size_t ro = (size_t)y * WNUM;
                    if (xok)  { pa0[r] = Ab[ro + xg];  pb0[r] = Bb[ro + xg]; }
                    if (x2ok) { pa1[r] = Ab[ro + xg2]; pb1[r] = Bb[ro + xg2]; }
                }
            }
        }
        __syncthreads();
        bool emit = (g >= RAMPG);
#pragma unroll
        for (int r = 0; r < RPG; ++r) {
            float sA=0.f, sB=0.f;
#pragma unroll
            for (int d = 0; d < KWIN; ++d) {
                sA += rowA[r][t + d];
                sB += rowB[r][t + d];
            }
            vA += sA - ring[0][slot][t]; ring[0][slot][t] = sA;
            vB += sB - ring[1][slot][t]; ring[1][slot][t] = sB;
            slot = (slot + 1 == KWIN) ? 0 : slot + 1;
            if (emit) {
                int k = g * RPG + r;
                int yout = ys + k - 2 * RR;
                float mA = vA * INV_KK;
                float mB = vB * INV_KK;
                size_t off = (size_t)yout * WNUM + x0 + t;
                float refined = mA * Ib[off] + mB;
                float mask = fminf(fmaxf(refined, 0.f), 1.f);
                partial += mask * Sb[off];
            }
        }
        __syncthreads();
    }
#pragma unroll
    for (int off = 32; off > 0; off >>= 1)
        partial += __shfl_down(partial, off);
    if ((t & 63) == 0) red[t >> 6] = partial;
    __syncthreads();
    if (t == 0) atomicAdd(loss_out, (red[0] + red[1]) * INV_NUMEL);
}

extern "C" void kernel_launch(void* const* d_in, const int* in_sizes, int n_in,
                              void* d_out, int out_size, void* d_ws, size_t ws_size,
                              hipStream_t stream) {
    const float* outp = (const float*)d_in[0];
    const float* inp  = (const float*)d_in[1];
    float* ws = (float*)d_ws;

    hipMemsetAsync(d_out, 0, sizeof(float), stream);

    if (ws_size >= (size_t)8 * NPLANE * sizeof(float)) {
        float* PI  = ws;
        float* PS  = ws + (size_t)1 * NPLANE;
        float* HI  = ws + (size_t)2 * NPLANE;
        float* HP  = ws + (size_t)3 * NPLANE;
        float* HIp = ws + (size_t)4 * NPLANE;
        float* HII = ws + (size_t)5 * NPLANE;
        float* Pa  = ws + (size_t)6 * NPLANE;
        float* Pb  = ws + (size_t)7 * NPLANE;
        float* Ha  = HI;   // HI/HP dead after v_ab
        float* Hb  = HP;

        prep_h<<<BNUM * HNUM, 128, 0, stream>>>(outp, inp, PI, PS, HI, HP, HIp, HII);
        dim3 vg(WNUM / 128, HNUM / YSEG, BNUM);   // 4 x 16 x 16 = 1024
        v_ab<<<vg, 128, 0, stream>>>(HI, HP, HIp, HII, Pa, Pb);
        h_mask<<<BNUM * HNUM, 128, 0, stream>>>(Pa, Pb, Ha, Hb);
        v_mask_loss<<<vg, 128, 0, stream>>>(Ha, Hb, PI, PS, (float*)d_out);
    } else {
        float* PI = ws;
        float* PP = ws + (size_t)NPLANE;
        float* PS = ws + (size_t)2 * NPLANE;
        float* PA = ws + (size_t)3 * NPLANE;
        float* PB = ws + (size_t)4 * NPLANE;
        prep_kernel<<<NPLANE / (256 * 4), 256, 0, stream>>>(outp, inp, PI, PP, PS);
        dim3 grid_ab(WNUM / STRIP, HNUM / SEG_AB, BNUM);
        boxc_ab<<<grid_ab, STRIP, 0, stream>>>(PI, PP, PA, PB);
        dim3 grid_ml(WNUM / STRIP, HNUM / SEG_ML, BNUM);
        boxc_mask_loss<<<grid_ml, STRIP, 0, stream>>>(PA, PB, PI, PS, (float*)d_out);
    }
}